// Round 10
// baseline (277.147 us; speedup 1.0000x reference)
//
#include <hip/hip_runtime.h>
#include <hip/hip_bf16.h>
#include <math.h>

#define BD 8        // batch
#define TD 1024     // T
#define CD 1024     // C
#define PD 100      // patterns
#define KS 16       // K-split for hidden GEMMs
#define KW (CD / KS)   // 64
#define SEG 2048    // floats per out-block segment (8 KB)
#define LAMBDA 0.1f
#define SIM_THR 0.5f

typedef float f4 __attribute__((ext_vector_type(4)));

// -------- device-global scratch (fully rewritten each call; deterministic) --
__device__ float    g_pctx[KS][BD][CD];   // k-partials of context hidden
__device__ float    g_ptrg[KS][PD][CD];   // k-partials of trigger hidden
__device__ float    g_wd[PD];             // dense gated weights, lambda folded in
__device__ float    g_wc[PD];             // compacted weights
__device__ unsigned g_poff[PD];           // compacted plane element-offsets
__device__ int      g_nnz;
__device__ float    g_sink[8192];         // stream-probe live sink

// -------- K1: partial hidden = X @ W1part over a 64-wide K slice -----------
__global__ __launch_bounds__(256) void hidden_kernel(const float* __restrict__ context,
                                                     const float* __restrict__ triggers,
                                                     const float* __restrict__ W1) {
    const int c  = blockIdx.x * 256 + threadIdx.x;   // output column
    const int kz = blockIdx.z;
    const int k0 = kz * KW;
    const bool is_ctx = (blockIdx.y == 0);
    const int  ych = blockIdx.y - 1;                 // trigger chunk 0..9
    const float* __restrict__ W1p = is_ctx ? W1 : (W1 + (size_t)CD * CD);
    const float* __restrict__ src = is_ctx ? context : (triggers + (size_t)ych * 10 * CD);
    float* __restrict__ dst = is_ctx ? &g_pctx[kz][0][0] : &g_ptrg[kz][ych * 10][0];
    const int nrows = is_ctx ? 8 : 10;

    __shared__ float s_src[10][KW];
    for (int t = threadIdx.x; t < 10 * KW; t += 256) {
        const int r = t >> 6, k = t & (KW - 1);
        s_src[r][k] = src[(size_t)(r < nrows ? r : 0) * CD + k0 + k];
    }
    __syncthreads();

    float acc[10];
#pragma unroll
    for (int i = 0; i < 10; ++i) acc[i] = 0.f;

#pragma unroll 8
    for (int kk = 0; kk < KW; ++kk) {
        const float wv = W1p[(size_t)(k0 + kk) * CD + c];
#pragma unroll
        for (int i = 0; i < 10; ++i)
            acc[i] = fmaf(s_src[i][kk], wv, acc[i]);
    }
#pragma unroll
    for (int i = 0; i < 10; ++i)
        if (i < nrows) dst[(size_t)i * CD + c] = acc[i];
}

// -------- K2: per-pattern score -> gated weight (lambda folded) -------------
__global__ __launch_bounds__(512) void score_kernel(const float* __restrict__ b1,
                                                    const float* __restrict__ W2,
                                                    const float* __restrict__ b2,
                                                    const float* __restrict__ conf) {
    const int p = blockIdx.x;
    __shared__ float s_h[CD];
    __shared__ float s_logit[BD];

    for (int c = threadIdx.x; c < CD; c += 512) {
        float v = b1[c];
#pragma unroll
        for (int kz = 0; kz < KS; ++kz) v += g_ptrg[kz][p][c];
        s_h[c] = v;
    }
    __syncthreads();

    const int b = threadIdx.x >> 6, lane = threadIdx.x & 63;
    float sum = 0.f;
    for (int c = lane; c < CD; c += 64) {
        float v = s_h[c];
#pragma unroll
        for (int kz = 0; kz < KS; ++kz) v += g_pctx[kz][b][c];
        sum = fmaf(fmaxf(v, 0.f), W2[c], sum);
    }
#pragma unroll
    for (int off = 32; off > 0; off >>= 1) sum += __shfl_down(sum, off);
    if (lane == 0) s_logit[b] = sum + b2[0];
    __syncthreads();
    if (threadIdx.x == 0) {
        float s = 0.f;
#pragma unroll
        for (int bb = 0; bb < BD; ++bb) s += 1.f / (1.f + expf(-s_logit[bb]));
        s *= (1.f / BD);
        g_wd[p] = (s > SIM_THR) ? s * conf[p] * LAMBDA : 0.f;
    }
}

// -------- K3: compact nonzero weights (deterministic order) -----------------
__global__ void compact_kernel() {
    if (threadIdx.x == 0) {
        int n = 0;
        for (int q = 0; q < PD; ++q) {
            const float w = g_wd[q];
            if (w != 0.f) {
                g_wc[n]   = w;
                g_poff[n] = (unsigned)(q * (TD * TD));
                ++n;
            }
        }
        g_nnz = n;
    }
}

// -------- K4: out = attn + sum_t w[t]*biases[idx[t]]  (wave-owns-plane) -----
// DENSE=false: compacted n planes (real path). DENSE=true: all 100 planes,
// zeros contribute exactly 0 -> identical output (probe for n / rate).
template <bool DENSE>
__global__ __launch_bounds__(256) void out_kernel(const float* __restrict__ attn,
                                                  const float* __restrict__ biases,
                                                  float* __restrict__ out) {
    __shared__ float    s_w[PD];
    __shared__ unsigned s_off[PD];
    __shared__ float    s_part[4][SEG];     // 32 KB
    const int n = DENSE ? PD : g_nnz;
    if (threadIdx.x < PD) {
        if (DENSE) {
            s_w[threadIdx.x]   = g_wd[threadIdx.x];
            s_off[threadIdx.x] = (unsigned)(threadIdx.x * (TD * TD));
        } else if (threadIdx.x < n) {
            s_w[threadIdx.x]   = g_wc[threadIdx.x];
            s_off[threadIdx.x] = g_poff[threadIdx.x];
        }
    }
    __syncthreads();

    const int wv = threadIdx.x >> 6, lane = threadIdx.x & 63;
    const size_t seg = (size_t)blockIdx.x * SEG;

    f4 acc[8];
#pragma unroll
    for (int j = 0; j < 8; ++j) acc[j] = (f4){0.f, 0.f, 0.f, 0.f};

    for (int t = wv; t < n; t += 4) {
        const float w = s_w[t];
        const float* bp = biases + (size_t)s_off[t] + seg + (size_t)lane * 4;
        f4 v[8];
#pragma unroll
        for (int j = 0; j < 8; ++j) v[j] = *(const f4*)(bp + j * 256);
#pragma unroll
        for (int j = 0; j < 8; ++j) {
            acc[j].x = fmaf(w, v[j].x, acc[j].x);
            acc[j].y = fmaf(w, v[j].y, acc[j].y);
            acc[j].z = fmaf(w, v[j].z, acc[j].z);
            acc[j].w = fmaf(w, v[j].w, acc[j].w);
        }
    }

#pragma unroll
    for (int j = 0; j < 8; ++j)
        *(f4*)&s_part[wv][j * 256 + lane * 4] = acc[j];
    __syncthreads();

    const int e = threadIdx.x * 8;
    f4 r0 = (f4){0.f, 0.f, 0.f, 0.f}, r1 = r0;
#pragma unroll
    for (int w2 = 0; w2 < 4; ++w2) {
        r0 += *(const f4*)&s_part[w2][e];
        r1 += *(const f4*)&s_part[w2][e + 4];
    }

#pragma unroll
    for (int b = 0; b < BD; ++b) {
        const size_t off = (size_t)b * TD * TD + seg + (size_t)e;
        const f4 a0 = *(const f4*)(attn + off);
        const f4 a1 = *(const f4*)(attn + off + 4);
        __builtin_nontemporal_store(a0 + r0, (f4*)(out + off));
        __builtin_nontemporal_store(a1 + r1, (f4*)(out + off + 4));
    }
}

// -------- K5: stream probe — pure sequential read of the 400 MB biases ------
// grid 2048x256, grid-stride f4; wave-sum written to g_sink (live, determin.).
__global__ __launch_bounds__(256) void stream_probe(const float* __restrict__ biases) {
    const size_t N4 = (size_t)PD * TD * TD / 4;
    const size_t stride = (size_t)gridDim.x * blockDim.x;
    f4 acc = {0.f, 0.f, 0.f, 0.f};
    for (size_t i = (size_t)blockIdx.x * blockDim.x + threadIdx.x; i < N4; i += stride)
        acc += *(const f4*)(biases + i * 4);
    float s = acc.x + acc.y + acc.z + acc.w;
#pragma unroll
    for (int off = 32; off > 0; off >>= 1) s += __shfl_down(s, off);
    if ((threadIdx.x & 63) == 0)
        g_sink[(blockIdx.x * 4) + (threadIdx.x >> 6)] = s;
}

extern "C" void kernel_launch(void* const* d_in, const int* in_sizes, int n_in,
                              void* d_out, int out_size, void* d_ws, size_t ws_size,
                              hipStream_t stream) {
    const float* attn     = (const float*)d_in[0];
    const float* context  = (const float*)d_in[1];
    const float* triggers = (const float*)d_in[2];
    const float* biases   = (const float*)d_in[3];
    const float* conf     = (const float*)d_in[4];
    const float* W1       = (const float*)d_in[5];
    const float* b1       = (const float*)d_in[6];
    const float* W2       = (const float*)d_in[7];
    const float* b2       = (const float*)d_in[8];
    float* out = (float*)d_out;

    hipLaunchKernelGGL(hidden_kernel, dim3(CD / 256, 11, KS), dim3(256), 0, stream,
                       context, triggers, W1);
    hipLaunchKernelGGL(score_kernel, dim3(PD), dim3(512), 0, stream, b1, W2, b2, conf);
    hipLaunchKernelGGL(compact_kernel, dim3(1), dim3(64), 0, stream);
    // real path (known T_out from R9 probe)
    hipLaunchKernelGGL((out_kernel<false>), dim3(TD * TD / SEG), dim3(256), 0, stream,
                       attn, biases, out);
    // probe 1: sequential-read ceiling of the biases buffer (~400 MB)
    hipLaunchKernelGGL(stream_probe, dim3(2048), dim3(256), 0, stream, biases);
    // probe 2: dense 100-plane out (idempotent, last writer -> output correct)
    hipLaunchKernelGGL((out_kernel<true>), dim3(TD * TD / SEG), dim3(256), 0, stream,
                       attn, biases, out);
}

// Round 11
// 103.004 us; speedup vs baseline: 2.6906x; 2.6906x over previous
//
#include <hip/hip_runtime.h>
#include <hip/hip_bf16.h>
#include <math.h>

#define BD 8        // batch
#define TD 1024     // T
#define CD 1024     // C
#define PD 100      // patterns
#define KS 16       // K-split for hidden GEMMs
#define KW (CD / KS)   // 64
#define SEG 2048    // floats per out-block segment (8 KB)
#define TT (TD * TD)
#define SPLITQ 48   // planes q < SPLITQ load cacheable (L3-resident set)
#define LAMBDA 0.1f
#define SIM_THR 0.5f

typedef float f4 __attribute__((ext_vector_type(4)));

// -------- device-global scratch (fully rewritten each call; deterministic) --
__device__ float g_pctx[KS][BD][CD];   // k-partials of context hidden
__device__ float g_ptrg[KS][PD][CD];   // k-partials of trigger hidden
__device__ float g_ctxb[BD][CD];       // b1 + sum_kz pctx (pre-summed once)
__device__ float g_wd[PD];             // dense gated weights, lambda folded in

// -------- K1: partial hidden = X @ W1part over a 64-wide K slice -----------
// grid = (CD/256, 11, KS): y==0 -> context (8 rows), y=1..10 -> trigger chunk
__global__ __launch_bounds__(256) void hidden_kernel(const float* __restrict__ context,
                                                     const float* __restrict__ triggers,
                                                     const float* __restrict__ W1) {
    const int c  = blockIdx.x * 256 + threadIdx.x;   // output column
    const int kz = blockIdx.z;
    const int k0 = kz * KW;
    const bool is_ctx = (blockIdx.y == 0);
    const int  ych = blockIdx.y - 1;                 // trigger chunk 0..9
    const float* __restrict__ W1p = is_ctx ? W1 : (W1 + (size_t)CD * CD);
    const float* __restrict__ src = is_ctx ? context : (triggers + (size_t)ych * 10 * CD);
    float* __restrict__ dst = is_ctx ? &g_pctx[kz][0][0] : &g_ptrg[kz][ych * 10][0];
    const int nrows = is_ctx ? 8 : 10;

    __shared__ float s_src[10][KW];
    for (int t = threadIdx.x; t < 10 * KW; t += 256) {
        const int r = t >> 6, k = t & (KW - 1);
        s_src[r][k] = src[(size_t)(r < nrows ? r : 0) * CD + k0 + k];
    }
    __syncthreads();

    float acc[10];
#pragma unroll
    for (int i = 0; i < 10; ++i) acc[i] = 0.f;

#pragma unroll 8
    for (int kk = 0; kk < KW; ++kk) {
        const float wv = W1p[(size_t)(k0 + kk) * CD + c];
#pragma unroll
        for (int i = 0; i < 10; ++i)
            acc[i] = fmaf(s_src[i][kk], wv, acc[i]);
    }
#pragma unroll
    for (int i = 0; i < 10; ++i)
        if (i < nrows) dst[(size_t)i * CD + c] = acc[i];
}

// -------- K2: ctxb[b][c] = b1[c] + sum_kz pctx[kz][b][c]  (once, not x100) --
// grid = (32), block 256: one thread per (b,c) element.
__global__ __launch_bounds__(256) void ctxsum_kernel(const float* __restrict__ b1) {
    const int idx = blockIdx.x * 256 + threadIdx.x;   // 0..8191
    const int b = idx >> 10, c = idx & (CD - 1);
    float v = b1[c];
#pragma unroll
    for (int kz = 0; kz < KS; ++kz) v += g_pctx[kz][b][c];
    g_ctxb[b][c] = v;
}

// -------- K3: per-pattern score -> gated weight (lambda folded) -------------
// grid = (PD), block 512: wave w handles batch row b=w.
__global__ __launch_bounds__(512) void score_kernel(const float* __restrict__ W2,
                                                    const float* __restrict__ b2,
                                                    const float* __restrict__ conf) {
    const int p = blockIdx.x;
    __shared__ float s_h[CD];       // sum_kz trg partials (b1 lives in ctxb)
    __shared__ float s_logit[BD];

    for (int c = threadIdx.x; c < CD; c += 512) {
        float v = 0.f;
#pragma unroll
        for (int kz = 0; kz < KS; ++kz) v += g_ptrg[kz][p][c];
        s_h[c] = v;
    }
    __syncthreads();

    const int b = threadIdx.x >> 6, lane = threadIdx.x & 63;
    float sum = 0.f;
    for (int c = lane; c < CD; c += 64) {
        const float v = s_h[c] + g_ctxb[b][c];
        sum = fmaf(fmaxf(v, 0.f), W2[c], sum);
    }
#pragma unroll
    for (int off = 32; off > 0; off >>= 1) sum += __shfl_down(sum, off);
    if (lane == 0) s_logit[b] = sum + b2[0];
    __syncthreads();
    if (threadIdx.x == 0) {
        float s = 0.f;
#pragma unroll
        for (int bb = 0; bb < BD; ++bb) s += 1.f / (1.f + expf(-s_logit[bb]));
        s *= (1.f / BD);
        g_wd[p] = (s > SIM_THR) ? s * conf[p] * LAMBDA : 0.f;
    }
}

// -------- K4: out = attn + sum_t w[t]*biases[idx[t]]  (wave-owns-plane) -----
// In-block ballot compaction (q-ascending). Planes q<SPLITQ: cacheable loads
// (kept L3-resident across graph replays); q>=SPLITQ: nontemporal (no alloc).
__global__ __launch_bounds__(256) void out_kernel(const float* __restrict__ attn,
                                                  const float* __restrict__ biases,
                                                  float* __restrict__ out) {
    __shared__ float    s_w[PD];
    __shared__ unsigned s_off[PD];
    __shared__ int      s_n;
    __shared__ float    s_part[4][SEG];     // 32 KB

    if (threadIdx.x < 64) {                 // wave 0: parallel compaction
        const int lane = threadIdx.x;
        const float w0 = g_wd[lane];
        const float w1 = (lane < PD - 64) ? g_wd[lane + 64] : 0.f;
        const unsigned long long m0 = __ballot(w0 != 0.f);
        const unsigned long long m1 = __ballot(w1 != 0.f);
        const unsigned long long below = (1ull << lane) - 1;
        const int c0 = __popcll(m0);
        if (w0 != 0.f) {
            const int i = __popcll(m0 & below);
            s_w[i] = w0; s_off[i] = (unsigned)(lane * TT);
        }
        if (w1 != 0.f) {
            const int i = c0 + __popcll(m1 & below);
            s_w[i] = w1; s_off[i] = (unsigned)((lane + 64) * TT);
        }
        if (lane == 0) s_n = c0 + __popcll(m1);
    }
    __syncthreads();
    const int n = s_n;

    const int wv = threadIdx.x >> 6, lane = threadIdx.x & 63;
    const size_t seg = (size_t)blockIdx.x * SEG;

    f4 acc[8];
#pragma unroll
    for (int j = 0; j < 8; ++j) acc[j] = (f4){0.f, 0.f, 0.f, 0.f};

    for (int t = wv; t < n; t += 4) {
        const float w = s_w[t];
        const float* bp = biases + (size_t)s_off[t] + seg + (size_t)lane * 4;
        f4 v[8];
        if (s_off[t] < (unsigned)(SPLITQ * TT)) {       // wave-uniform branch
#pragma unroll
            for (int j = 0; j < 8; ++j) v[j] = *(const f4*)(bp + j * 256);
        } else {
#pragma unroll
            for (int j = 0; j < 8; ++j)
                v[j] = __builtin_nontemporal_load((const f4*)(bp + j * 256));
        }
#pragma unroll
        for (int j = 0; j < 8; ++j) {
            acc[j].x = fmaf(w, v[j].x, acc[j].x);
            acc[j].y = fmaf(w, v[j].y, acc[j].y);
            acc[j].z = fmaf(w, v[j].z, acc[j].z);
            acc[j].w = fmaf(w, v[j].w, acc[j].w);
        }
    }

#pragma unroll
    for (int j = 0; j < 8; ++j)
        *(f4*)&s_part[wv][j * 256 + lane * 4] = acc[j];
    __syncthreads();

    const int e = threadIdx.x * 8;
    f4 r0 = (f4){0.f, 0.f, 0.f, 0.f}, r1 = r0;
#pragma unroll
    for (int w2 = 0; w2 < 4; ++w2) {
        r0 += *(const f4*)&s_part[w2][e];
        r1 += *(const f4*)&s_part[w2][e + 4];
    }

#pragma unroll
    for (int b = 0; b < BD; ++b) {
        const size_t off = (size_t)b * TT + seg + (size_t)e;
        const f4 a0 = *(const f4*)(attn + off);
        const f4 a1 = *(const f4*)(attn + off + 4);
        __builtin_nontemporal_store(a0 + r0, (f4*)(out + off));
        __builtin_nontemporal_store(a1 + r1, (f4*)(out + off + 4));
    }
}

extern "C" void kernel_launch(void* const* d_in, const int* in_sizes, int n_in,
                              void* d_out, int out_size, void* d_ws, size_t ws_size,
                              hipStream_t stream) {
    const float* attn     = (const float*)d_in[0];  // (B,T,T)
    const float* context  = (const float*)d_in[1];  // (B,C)
    const float* triggers = (const float*)d_in[2];  // (P,C)
    const float* biases   = (const float*)d_in[3];  // (P,T,T)
    const float* conf     = (const float*)d_in[4];  // (P,)
    const float* W1       = (const float*)d_in[5];  // (2C,C)
    const float* b1       = (const float*)d_in[6];  // (C,)
    const float* W2       = (const float*)d_in[7];  // (C,)
    const float* b2       = (const float*)d_in[8];  // (1,)
    float* out = (float*)d_out;

    hipLaunchKernelGGL(hidden_kernel, dim3(CD / 256, 11, KS), dim3(256), 0, stream,
                       context, triggers, W1);
    hipLaunchKernelGGL(ctxsum_kernel, dim3(BD * CD / 256), dim3(256), 0, stream, b1);
    hipLaunchKernelGGL(score_kernel, dim3(PD), dim3(512), 0, stream, W2, b2, conf);
    hipLaunchKernelGGL(out_kernel, dim3(TT / SEG), dim3(256), 0, stream, attn, biases, out);
}